// Round 4
// baseline (962.327 us; speedup 1.0000x reference)
//
#include <hip/hip_runtime.h>
#include <cstdint>
#include <cstddef>

#define N_ROWS 16384   // B*T
#define KCODES 4096
#define DIM    256

typedef _Float16 f16x8 __attribute__((ext_vector_type(8)));
typedef float    f32x4 __attribute__((ext_vector_type(4)));

__device__ inline void gload16(const void* g, void* l) {
    __builtin_amdgcn_global_load_lds((const __attribute__((address_space(1))) void*)g,
                                     (__attribute__((address_space(3))) void*)l, 16, 0, 0);
}

// -------- kernel 1: inverse L2 norms of z rows and codebook rows --------
__global__ __launch_bounds__(256) void norms_kernel(
    const float* __restrict__ z, const float* __restrict__ cb,
    float* __restrict__ zinv, float* __restrict__ cinv)
{
    int wid  = blockIdx.x * 4 + (threadIdx.x >> 6);
    int lane = threadIdx.x & 63;
    const float* src;
    float* dst;
    if (wid < N_ROWS) { src = z + (size_t)wid * DIM; dst = zinv + wid; }
    else {
        int r = wid - N_ROWS;
        src = cb + (size_t)r * DIM; dst = cinv + r;
    }
    float4 v = reinterpret_cast<const float4*>(src)[lane];
    float s = v.x*v.x + v.y*v.y + v.z*v.z + v.w*v.w;
    #pragma unroll
    for (int m = 1; m <= 32; m <<= 1) s += __shfl_xor(s, m);
    if (lane == 0) *dst = 1.0f / fmaxf(sqrtf(s), 1e-12f);
}

// -------- kernel 2: normalize, x16 scale, f16 hi/lo split, fragment order --------
// K-tile = 32. Tile (btile, kt) = 128 rows x 32 k. Layout: [frag(8)][lane(64)][8 f16].
__global__ __launch_bounds__(256) void prep_kernel(
    const float* __restrict__ src, const float* __restrict__ inv,
    _Float16* __restrict__ ghi, _Float16* __restrict__ glo)
{
    const int kt = blockIdx.x;        // 0..7
    const int btile = blockIdx.y;
    const int t = threadIdx.x, lane = t & 63, wid = t >> 6;
    #pragma unroll
    for (int fi = 0; fi < 2; ++fi) {
        int frag = wid * 2 + fi;      // 0..7 (16-row groups)
        int r  = btile * 128 + frag * 16 + (lane & 15);
        int k0 = kt * 32 + ((lane >> 4) << 3);
        const float4* p = reinterpret_cast<const float4*>(src + (size_t)r * DIM + k0);
        float4 v0 = p[0], v1 = p[1];
        float s = inv[r] * 16.0f;
        float x[8] = {v0.x*s, v0.y*s, v0.z*s, v0.w*s, v1.x*s, v1.y*s, v1.z*s, v1.w*s};
        f16x8 h, l;
        #pragma unroll
        for (int e = 0; e < 8; ++e) {
            _Float16 he = (_Float16)x[e];
            h[e] = he;
            l[e] = (_Float16)((x[e] - (float)he) * 4096.0f);
        }
        size_t base = ((size_t)(btile * 8 + kt)) * 4096 + (size_t)frag * 512 + lane * 8;
        *reinterpret_cast<f16x8*>(ghi + base) = h;
        *reinterpret_cast<f16x8*>(glo + base) = l;
    }
}

// -------- kernel 3: MFMA split-precision GEMM + gumbel + per-tile argmax --------
// 128x128 tile, BK=32, SINGLE 32KB LDS buffer -> 4 blocks/CU (occupancy lever).
__global__ __launch_bounds__(256, 4) void gemm_argmax_kernel(
    const _Float16* __restrict__ zhi, const _Float16* __restrict__ zlo,
    const _Float16* __restrict__ chi, const _Float16* __restrict__ clo,
    const float* __restrict__ u,
    float2* __restrict__ partial)   // [N_ROWS][32]
{
    __shared__ __align__(16) char lds[32768];

    // bijective XCD swizzle (4096 % 8 == 0): contiguous 512-block chunk per XCD
    int bid = blockIdx.x;
    int swz = (bid & 7) * 512 + (bid >> 3);
    const int brow = swz >> 5;      // 0..127
    const int bcol = swz & 31;      // 0..31

    const int t = threadIdx.x, lane = t & 63;
    const int wave = t >> 6, wm = wave >> 1, wn = wave & 1;

    const _Float16* zh = zhi + (size_t)(brow * 8) * 4096;
    const _Float16* zl = zlo + (size_t)(brow * 8) * 4096;
    const _Float16* ch = chi + (size_t)(bcol * 8) * 4096;
    const _Float16* cl = clo + (size_t)(bcol * 8) * 4096;

    f32x4 accm[4][4], accc[4][4];
    #pragma unroll
    for (int i = 0; i < 4; ++i)
        #pragma unroll
        for (int j = 0; j < 4; ++j) {
            accm[i][j] = (f32x4){0.f,0.f,0.f,0.f};
            accc[i][j] = (f32x4){0.f,0.f,0.f,0.f};
        }

    #pragma unroll 1
    for (int kt = 0; kt < 8; ++kt) {
        // stage this K-slab (8 x 16B per thread, linear LDS, conflict-free)
        #pragma unroll
        for (int c = 0; c < 2; ++c) {
            int frag = wave * 2 + c;                      // 0..7, wave-uniform
            int go = kt * 4096 + frag * 512 + lane * 8;   // halfs
            int lo = frag * 1024 + lane * 16;             // bytes
            gload16(zh + go, lds + 0     + lo);
            gload16(zl + go, lds + 8192  + lo);
            gload16(ch + go, lds + 16384 + lo);
            gload16(cl + go, lds + 24576 + lo);
        }
        __syncthreads();   // vmcnt(0): slab ready

        f16x8 ah[4], al[4], bh[4], bl[4];
        #pragma unroll
        for (int i = 0; i < 4; ++i) {
            int ao = (wm * 4 + i) * 1024 + lane * 16;
            ah[i] = *reinterpret_cast<const f16x8*>(lds + ao);
            al[i] = *reinterpret_cast<const f16x8*>(lds + 8192 + ao);
            int bo = (wn * 4 + i) * 1024 + lane * 16;
            bh[i] = *reinterpret_cast<const f16x8*>(lds + 16384 + bo);
            bl[i] = *reinterpret_cast<const f16x8*>(lds + 24576 + bo);
        }
        #pragma unroll
        for (int i = 0; i < 4; ++i)
            #pragma unroll
            for (int j = 0; j < 4; ++j) {
                accm[i][j] = __builtin_amdgcn_mfma_f32_16x16x32_f16(ah[i], bh[j], accm[i][j], 0, 0, 0);
                accc[i][j] = __builtin_amdgcn_mfma_f32_16x16x32_f16(ah[i], bl[j], accc[i][j], 0, 0, 0);
                accc[i][j] = __builtin_amdgcn_mfma_f32_16x16x32_f16(al[i], bh[j], accc[i][j], 0, 0, 0);
            }
        __syncthreads();   // lgkm drained: safe to overwrite the buffer
    }

    // epilogue: S = (accm + accc/4096)/256 + gumbel; per-row argmax over 128 cols
    float2* sbest = reinterpret_cast<float2*>(lds);   // [128][2]
    const float isc = 1.0f / 4096.0f;
    const float osc = 1.0f / 256.0f;
    const int l15 = lane & 15;

    #pragma unroll
    for (int i = 0; i < 4; ++i) {
        #pragma unroll
        for (int q = 0; q < 4; ++q) {
            int rloc = wm * 64 + i * 16 + ((lane >> 4) << 2) + q;
            int grow = brow * 128 + rloc;
            const float* urow = u + (size_t)grow * KCODES + bcol * 128 + wn * 64 + l15;
            float best = -3.0e38f;
            int bidx = 1 << 30;
            #pragma unroll
            for (int j = 0; j < 4; ++j) {
                float s = (accm[i][j][q] + accc[i][j][q] * isc) * osc;
                float uu = urow[j * 16];
                float y = -__logf(uu + 1e-10f);
                float g = -__logf(y + 1e-10f);
                float v = s + g;
                int ci = bcol * 128 + wn * 64 + j * 16 + l15;
                if (v > best || (v == best && ci < bidx)) { best = v; bidx = ci; }
            }
            #pragma unroll
            for (int m = 1; m <= 8; m <<= 1) {
                float ov = __shfl_xor(best, m);
                int   oi = __shfl_xor(bidx, m);
                if (ov > best || (ov == best && oi < bidx)) { best = ov; bidx = oi; }
            }
            if (l15 == 0) sbest[rloc * 2 + wn] = make_float2(best, (float)bidx);
        }
    }
    __syncthreads();
    if (t < 128) {
        float2 a = sbest[t * 2], b = sbest[t * 2 + 1];
        float2 w = (b.x > a.x || (b.x == a.x && b.y < a.y)) ? b : a;
        partial[(size_t)(brow * 128 + t) * 32 + bcol] = w;
    }
}

// -------- kernel 4: reduce 32 partials/row, gather codebook row, commitment partial --------
__global__ __launch_bounds__(256) void reduce_gather_kernel(
    const float2* __restrict__ partial,
    const float* __restrict__ cb, const float* __restrict__ z,
    float* __restrict__ zq, float* __restrict__ emb,
    float* __restrict__ idx_out, float* __restrict__ commit_part)
{
    int row  = blockIdx.x * 4 + (threadIdx.x >> 6);
    int lane = threadIdx.x & 63;
    float v = -3.0e38f;
    int   bi = 0x7fffffff;
    if (lane < 32) {
        float2 p = partial[(size_t)row * 32 + lane];
        v = p.x; bi = (int)p.y;
    }
    #pragma unroll
    for (int m = 1; m <= 32; m <<= 1) {
        float ov = __shfl_xor(v, m);
        int   oi = __shfl_xor(bi, m);
        if (ov > v || (ov == v && oi < bi)) { v = ov; bi = oi; }
    }
    float4 c  = reinterpret_cast<const float4*>(cb + (size_t)bi * DIM)[lane];
    reinterpret_cast<float4*>(zq  + (size_t)row * DIM)[lane] = c;
    reinterpret_cast<float4*>(emb + (size_t)row * DIM)[lane] = c;
    float4 zz = reinterpret_cast<const float4*>(z + (size_t)row * DIM)[lane];
    float dx = c.x - zz.x, dy = c.y - zz.y, dz = c.z - zz.z, dw = c.w - zz.w;
    float s = dx*dx + dy*dy + dz*dz + dw*dw;
    #pragma unroll
    for (int m = 1; m <= 32; m <<= 1) s += __shfl_xor(s, m);
    if (lane == 0) {
        idx_out[row]     = (float)bi;
        commit_part[row] = s;
    }
}

// -------- kernel 5: scalars --------
__global__ __launch_bounds__(256) void scalars_kernel(
    const float* __restrict__ commit_part, const float* __restrict__ usage,
    const int* __restrict__ step_ptr, float* __restrict__ out4)
{
    __shared__ float red[256];
    int t = threadIdx.x;

    float s = 0.f;
    for (int i = t; i < N_ROWS; i += 256) s += commit_part[i];
    red[t] = s; __syncthreads();
    for (int w = 128; w > 0; w >>= 1) { if (t < w) red[t] += red[t + w]; __syncthreads(); }
    float commitment = 0.5f * red[0] / 4194304.0f;
    __syncthreads();

    float us = 0.f;
    for (int i = t; i < KCODES; i += 256) us += usage[i];
    red[t] = us; __syncthreads();
    for (int w = 128; w > 0; w >>= 1) { if (t < w) red[t] += red[t + w]; __syncthreads(); }
    float usage_sum = red[0];
    __syncthreads();

    float e = 0.f;
    for (int i = t; i < KCODES; i += 256) {
        float p = (usage_sum > 0.f) ? usage[i] / (usage_sum + 1e-10f) : (1.0f / KCODES);
        e += p * logf(p + 1e-10f);
    }
    red[t] = e; __syncthreads();
    for (int w = 128; w > 0; w >>= 1) { if (t < w) red[t] += red[t + w]; __syncthreads(); }

    if (t == 0) {
        float entropy = -red[0];
        int step_after = step_ptr[0] + 1;
        float bonus_w = 0.05f * (1.0f - (float)step_after / 20000.0f);
        float eb = (step_after < 20000) ? (-bonus_w * entropy) : 0.0f;
        out4[0] = commitment;
        out4[1] = eb;
        out4[2] = expf(entropy);
        out4[3] = entropy;
    }
}

extern "C" void kernel_launch(void* const* d_in, const int* in_sizes, int n_in,
                              void* d_out, int out_size, void* d_ws, size_t ws_size,
                              hipStream_t stream)
{
    const float* z     = (const float*)d_in[0];
    const float* u     = (const float*)d_in[1];
    const float* cb    = (const float*)d_in[2];
    const float* usage = (const float*)d_in[3];
    const int*   step  = (const int*)d_in[4];

    float* out  = (float*)d_out;
    float* zq   = out;                 // 4194304
    float* emb  = out + 4194304;       // 4194304
    float* idxo = out + 8388608;       // 16384
    float* scal = out + 8404992;       // 4

    // prep arrays live in d_out's first 20 MB (dead until reduce_gather rewrites it)
    _Float16* zhi = (_Float16*)out;            // 8 MB
    _Float16* zlo = zhi + 4194304;             // 8 MB
    _Float16* chi = zlo + 4194304;             // 2 MB
    _Float16* clo = chi + 1048576;             // 2 MB

    float*  ws          = (float*)d_ws;
    float*  zinv        = ws;                    // 16384
    float*  cinv        = ws + 16384;            // 4096
    float*  commit_part = ws + 20480;            // 16384
    float2* partial     = (float2*)(ws + 36864); // 16384*32 float2 (4 MB)

    hipLaunchKernelGGL(norms_kernel, dim3(5120), dim3(256), 0, stream, z, cb, zinv, cinv);
    hipLaunchKernelGGL(prep_kernel, dim3(8, 128), dim3(256), 0, stream, z,  zinv, zhi, zlo);
    hipLaunchKernelGGL(prep_kernel, dim3(8, 32),  dim3(256), 0, stream, cb, cinv, chi, clo);
    hipLaunchKernelGGL(gemm_argmax_kernel, dim3(4096), dim3(256), 0, stream,
                       zhi, zlo, chi, clo, u, partial);
    hipLaunchKernelGGL(reduce_gather_kernel, dim3(4096), dim3(256), 0, stream,
                       partial, cb, z, zq, emb, idxo, commit_part);
    hipLaunchKernelGGL(scalars_kernel, dim3(1), dim3(256), 0, stream,
                       commit_part, usage, step, scal);
}

// Round 5
// 394.792 us; speedup vs baseline: 2.4376x; 2.4376x over previous
//
#include <hip/hip_runtime.h>
#include <cstdint>
#include <cstddef>

#define N_ROWS 16384   // B*T
#define KCODES 4096
#define DIM    256

typedef _Float16 f16x8 __attribute__((ext_vector_type(8)));
typedef float    f32x4 __attribute__((ext_vector_type(4)));

__device__ inline void gload16(const void* g, void* l) {
    __builtin_amdgcn_global_load_lds((const __attribute__((address_space(1))) void*)g,
                                     (__attribute__((address_space(3))) void*)l, 16, 0, 0);
}

// -------- kernel 1: inverse L2 norms of z rows and codebook rows --------
__global__ __launch_bounds__(256) void norms_kernel(
    const float* __restrict__ z, const float* __restrict__ cb,
    float* __restrict__ zinv, float* __restrict__ cinv)
{
    int wid  = blockIdx.x * 4 + (threadIdx.x >> 6);
    int lane = threadIdx.x & 63;
    const float* src;
    float* dst;
    if (wid < N_ROWS) { src = z + (size_t)wid * DIM; dst = zinv + wid; }
    else {
        int r = wid - N_ROWS;
        src = cb + (size_t)r * DIM; dst = cinv + r;
    }
    float4 v = reinterpret_cast<const float4*>(src)[lane];
    float s = v.x*v.x + v.y*v.y + v.z*v.z + v.w*v.w;
    #pragma unroll
    for (int m = 1; m <= 32; m <<= 1) s += __shfl_xor(s, m);
    if (lane == 0) *dst = 1.0f / fmaxf(sqrtf(s), 1e-12f);
}

// -------- kernel 2: normalize, x16 scale, f16 hi/lo split, fragment order --------
// K-tile = 32. Tile (btile, kt) = 128 rows x 32 k. Layout: [frag(8)][lane(64)][8 f16].
__global__ __launch_bounds__(256) void prep_kernel(
    const float* __restrict__ src, const float* __restrict__ inv,
    _Float16* __restrict__ ghi, _Float16* __restrict__ glo)
{
    const int kt = blockIdx.x;        // 0..7
    const int btile = blockIdx.y;
    const int t = threadIdx.x, lane = t & 63, wid = t >> 6;
    #pragma unroll
    for (int fi = 0; fi < 2; ++fi) {
        int frag = wid * 2 + fi;      // 0..7 (16-row groups)
        int r  = btile * 128 + frag * 16 + (lane & 15);
        int k0 = kt * 32 + ((lane >> 4) << 3);
        const float4* p = reinterpret_cast<const float4*>(src + (size_t)r * DIM + k0);
        float4 v0 = p[0], v1 = p[1];
        float s = inv[r] * 16.0f;
        float x[8] = {v0.x*s, v0.y*s, v0.z*s, v0.w*s, v1.x*s, v1.y*s, v1.z*s, v1.w*s};
        f16x8 h, l;
        #pragma unroll
        for (int e = 0; e < 8; ++e) {
            _Float16 he = (_Float16)x[e];
            h[e] = he;
            l[e] = (_Float16)((x[e] - (float)he) * 4096.0f);
        }
        size_t base = ((size_t)(btile * 8 + kt)) * 4096 + (size_t)frag * 512 + lane * 8;
        *reinterpret_cast<f16x8*>(ghi + base) = h;
        *reinterpret_cast<f16x8*>(glo + base) = l;
    }
}

// -------- kernel 3: MFMA split-precision GEMM + gumbel + per-tile argmax --------
// 128x128 tile, BK=32, single 32KB LDS buffer (4 blocks/CU), VGPR cap 256 (no spills).
__global__ __launch_bounds__(256, 2) void gemm_argmax_kernel(
    const _Float16* __restrict__ zhi, const _Float16* __restrict__ zlo,
    const _Float16* __restrict__ chi, const _Float16* __restrict__ clo,
    const float* __restrict__ u,
    float2* __restrict__ partial)   // [N_ROWS][32]
{
    __shared__ __align__(16) char lds[32768];

    // bijective XCD swizzle (4096 % 8 == 0): contiguous 512-block chunk per XCD
    int bid = blockIdx.x;
    int swz = (bid & 7) * 512 + (bid >> 3);
    const int brow = swz >> 5;      // 0..127
    const int bcol = swz & 31;      // 0..31

    const int t = threadIdx.x, lane = t & 63;
    const int wave = t >> 6, wm = wave >> 1, wn = wave & 1;

    const _Float16* zh = zhi + (size_t)(brow * 8) * 4096;
    const _Float16* zl = zlo + (size_t)(brow * 8) * 4096;
    const _Float16* ch = chi + (size_t)(bcol * 8) * 4096;
    const _Float16* cl = clo + (size_t)(bcol * 8) * 4096;

    f32x4 accm[4][4], accc[4][4];
    #pragma unroll
    for (int i = 0; i < 4; ++i)
        #pragma unroll
        for (int j = 0; j < 4; ++j) {
            accm[i][j] = (f32x4){0.f,0.f,0.f,0.f};
            accc[i][j] = (f32x4){0.f,0.f,0.f,0.f};
        }

    #pragma unroll 1
    for (int kt = 0; kt < 8; ++kt) {
        // stage this K-slab (8 x 16B per thread, linear LDS, conflict-free)
        #pragma unroll
        for (int c = 0; c < 2; ++c) {
            int frag = wave * 2 + c;                      // 0..7, wave-uniform
            int go = kt * 4096 + frag * 512 + lane * 8;   // halfs
            int lo = frag * 1024 + lane * 16;             // bytes
            gload16(zh + go, lds + 0     + lo);
            gload16(zl + go, lds + 8192  + lo);
            gload16(ch + go, lds + 16384 + lo);
            gload16(cl + go, lds + 24576 + lo);
        }
        __syncthreads();   // vmcnt(0): slab ready

        f16x8 ah[4], al[4], bh[4], bl[4];
        #pragma unroll
        for (int i = 0; i < 4; ++i) {
            int ao = (wm * 4 + i) * 1024 + lane * 16;
            ah[i] = *reinterpret_cast<const f16x8*>(lds + ao);
            al[i] = *reinterpret_cast<const f16x8*>(lds + 8192 + ao);
            int bo = (wn * 4 + i) * 1024 + lane * 16;
            bh[i] = *reinterpret_cast<const f16x8*>(lds + 16384 + bo);
            bl[i] = *reinterpret_cast<const f16x8*>(lds + 24576 + bo);
        }
        #pragma unroll
        for (int i = 0; i < 4; ++i)
            #pragma unroll
            for (int j = 0; j < 4; ++j) {
                accm[i][j] = __builtin_amdgcn_mfma_f32_16x16x32_f16(ah[i], bh[j], accm[i][j], 0, 0, 0);
                accc[i][j] = __builtin_amdgcn_mfma_f32_16x16x32_f16(ah[i], bl[j], accc[i][j], 0, 0, 0);
                accc[i][j] = __builtin_amdgcn_mfma_f32_16x16x32_f16(al[i], bh[j], accc[i][j], 0, 0, 0);
            }
        __syncthreads();   // safe to overwrite the buffer
    }

    // epilogue: S = (accm + accc/4096)/256 + gumbel; per-row argmax over 128 cols
    float2* sbest = reinterpret_cast<float2*>(lds);   // [128][2]
    const float isc = 1.0f / 4096.0f;
    const float osc = 1.0f / 256.0f;
    const int l15 = lane & 15;

    #pragma unroll
    for (int i = 0; i < 4; ++i) {
        #pragma unroll
        for (int q = 0; q < 4; ++q) {
            int rloc = wm * 64 + i * 16 + ((lane >> 4) << 2) + q;
            int grow = brow * 128 + rloc;
            const float* urow = u + (size_t)grow * KCODES + bcol * 128 + wn * 64 + l15;
            float best = -3.0e38f;
            int bidx = 1 << 30;
            #pragma unroll
            for (int j = 0; j < 4; ++j) {
                float s = (accm[i][j][q] + accc[i][j][q] * isc) * osc;
                float uu = urow[j * 16];
                float y = -__logf(uu + 1e-10f);
                float g = -__logf(y + 1e-10f);
                float v = s + g;
                int ci = bcol * 128 + wn * 64 + j * 16 + l15;
                if (v > best || (v == best && ci < bidx)) { best = v; bidx = ci; }
            }
            #pragma unroll
            for (int m = 1; m <= 8; m <<= 1) {
                float ov = __shfl_xor(best, m);
                int   oi = __shfl_xor(bidx, m);
                if (ov > best || (ov == best && oi < bidx)) { best = ov; bidx = oi; }
            }
            if (l15 == 0) sbest[rloc * 2 + wn] = make_float2(best, (float)bidx);
        }
    }
    __syncthreads();
    if (t < 128) {
        float2 a = sbest[t * 2], b = sbest[t * 2 + 1];
        float2 w = (b.x > a.x || (b.x == a.x && b.y < a.y)) ? b : a;
        partial[(size_t)(brow * 128 + t) * 32 + bcol] = w;
    }
}

// -------- kernel 4: reduce 32 partials/row, gather codebook row, commitment partial --------
__global__ __launch_bounds__(256) void reduce_gather_kernel(
    const float2* __restrict__ partial,
    const float* __restrict__ cb, const float* __restrict__ z,
    float* __restrict__ zq, float* __restrict__ emb,
    float* __restrict__ idx_out, float* __restrict__ commit_part)
{
    int row  = blockIdx.x * 4 + (threadIdx.x >> 6);
    int lane = threadIdx.x & 63;
    float v = -3.0e38f;
    int   bi = 0x7fffffff;
    if (lane < 32) {
        float2 p = partial[(size_t)row * 32 + lane];
        v = p.x; bi = (int)p.y;
    }
    #pragma unroll
    for (int m = 1; m <= 32; m <<= 1) {
        float ov = __shfl_xor(v, m);
        int   oi = __shfl_xor(bi, m);
        if (ov > v || (ov == v && oi < bi)) { v = ov; bi = oi; }
    }
    float4 c  = reinterpret_cast<const float4*>(cb + (size_t)bi * DIM)[lane];
    reinterpret_cast<float4*>(zq  + (size_t)row * DIM)[lane] = c;
    reinterpret_cast<float4*>(emb + (size_t)row * DIM)[lane] = c;
    float4 zz = reinterpret_cast<const float4*>(z + (size_t)row * DIM)[lane];
    float dx = c.x - zz.x, dy = c.y - zz.y, dz = c.z - zz.z, dw = c.w - zz.w;
    float s = dx*dx + dy*dy + dz*dz + dw*dw;
    #pragma unroll
    for (int m = 1; m <= 32; m <<= 1) s += __shfl_xor(s, m);
    if (lane == 0) {
        idx_out[row]     = (float)bi;
        commit_part[row] = s;
    }
}

// -------- kernel 5: scalars --------
__global__ __launch_bounds__(256) void scalars_kernel(
    const float* __restrict__ commit_part, const float* __restrict__ usage,
    const int* __restrict__ step_ptr, float* __restrict__ out4)
{
    __shared__ float red[256];
    int t = threadIdx.x;

    float s = 0.f;
    for (int i = t; i < N_ROWS; i += 256) s += commit_part[i];
    red[t] = s; __syncthreads();
    for (int w = 128; w > 0; w >>= 1) { if (t < w) red[t] += red[t + w]; __syncthreads(); }
    float commitment = 0.5f * red[0] / 4194304.0f;
    __syncthreads();

    float us = 0.f;
    for (int i = t; i < KCODES; i += 256) us += usage[i];
    red[t] = us; __syncthreads();
    for (int w = 128; w > 0; w >>= 1) { if (t < w) red[t] += red[t + w]; __syncthreads(); }
    float usage_sum = red[0];
    __syncthreads();

    float e = 0.f;
    for (int i = t; i < KCODES; i += 256) {
        float p = (usage_sum > 0.f) ? usage[i] / (usage_sum + 1e-10f) : (1.0f / KCODES);
        e += p * logf(p + 1e-10f);
    }
    red[t] = e; __syncthreads();
    for (int w = 128; w > 0; w >>= 1) { if (t < w) red[t] += red[t + w]; __syncthreads(); }

    if (t == 0) {
        float entropy = -red[0];
        int step_after = step_ptr[0] + 1;
        float bonus_w = 0.05f * (1.0f - (float)step_after / 20000.0f);
        float eb = (step_after < 20000) ? (-bonus_w * entropy) : 0.0f;
        out4[0] = commitment;
        out4[1] = eb;
        out4[2] = expf(entropy);
        out4[3] = entropy;
    }
}

extern "C" void kernel_launch(void* const* d_in, const int* in_sizes, int n_in,
                              void* d_out, int out_size, void* d_ws, size_t ws_size,
                              hipStream_t stream)
{
    const float* z     = (const float*)d_in[0];
    const float* u     = (const float*)d_in[1];
    const float* cb    = (const float*)d_in[2];
    const float* usage = (const float*)d_in[3];
    const int*   step  = (const int*)d_in[4];

    float* out  = (float*)d_out;
    float* zq   = out;                 // 4194304
    float* emb  = out + 4194304;       // 4194304
    float* idxo = out + 8388608;       // 16384
    float* scal = out + 8404992;       // 4

    // prep arrays live in d_out's first 20 MB (dead until reduce_gather rewrites it)
    _Float16* zhi = (_Float16*)out;            // 8 MB
    _Float16* zlo = zhi + 4194304;             // 8 MB
    _Float16* chi = zlo + 4194304;             // 2 MB
    _Float16* clo = chi + 1048576;             // 2 MB

    float*  ws          = (float*)d_ws;
    float*  zinv        = ws;                    // 16384
    float*  cinv        = ws + 16384;            // 4096
    float*  commit_part = ws + 20480;            // 16384
    float2* partial     = (float2*)(ws + 36864); // 16384*32 float2 (4 MB)

    hipLaunchKernelGGL(norms_kernel, dim3(5120), dim3(256), 0, stream, z, cb, zinv, cinv);
    hipLaunchKernelGGL(prep_kernel, dim3(8, 128), dim3(256), 0, stream, z,  zinv, zhi, zlo);
    hipLaunchKernelGGL(prep_kernel, dim3(8, 32),  dim3(256), 0, stream, cb, cinv, chi, clo);
    hipLaunchKernelGGL(gemm_argmax_kernel, dim3(4096), dim3(256), 0, stream,
                       zhi, zlo, chi, clo, u, partial);
    hipLaunchKernelGGL(reduce_gather_kernel, dim3(4096), dim3(256), 0, stream,
                       partial, cb, z, zq, emb, idxo, commit_part);
    hipLaunchKernelGGL(scalars_kernel, dim3(1), dim3(256), 0, stream,
                       commit_part, usage, step, scal);
}